// Round 1
// baseline (4108.815 us; speedup 1.0000x reference)
//
#include <hip/hip_runtime.h>
#include <hip/hip_bf16.h>

#define I_LEN 512
#define BSZ   8
#define HIDN  1024
#define NHEAD 16
#define HDIM  64
#define PLEN_ 1024
#define SCALE_F 0.125f
#define BIGNUM 1e30f
#define LN_EPS 1e-5f

typedef unsigned int   u32;
typedef unsigned short u16;

__device__ __forceinline__ float bflo(u32 w) { return __uint_as_float(w << 16); }
__device__ __forceinline__ float bfhi(u32 w) { return __uint_as_float(w & 0xffff0000u); }
__device__ __forceinline__ u16 f2bf(float x) {
  u32 u = __float_as_uint(x);
  return (u16)((u + 0x7fffu + ((u >> 16) & 1u)) >> 16);
}
__device__ __forceinline__ void bf8_to_f(const uint4 v, float* f) {
  f[0] = bflo(v.x); f[1] = bfhi(v.x);
  f[2] = bflo(v.y); f[3] = bfhi(v.y);
  f[4] = bflo(v.z); f[5] = bfhi(v.z);
  f[6] = bflo(v.w); f[7] = bfhi(v.w);
}

// ---------------- fp32 SGEMM 128x128x16, 256 thr, 8x8 microtile ----------------
// C[M][1024] = A[M][1024] @ B (+Res). TRANSB: B given as [1024 rows=outcol][1024 cols=k].
template<bool TRANSB, bool RES, bool CBF16>
__global__ __launch_bounds__(256)
void sgemm128(const float* __restrict__ A, const float* __restrict__ B,
              const float* __restrict__ Res, void* __restrict__ Cv) {
  constexpr int K = 1024, N = 1024;
  __shared__ float As[16][132];   // [k][m]
  __shared__ float Bs[16][132];   // [k][n]
  const int bm = blockIdx.y * 128, bn = blockIdx.x * 128;
  const int tid = threadIdx.x;
  const int ty = tid >> 4, tx = tid & 15;
  float acc[8][8];
#pragma unroll
  for (int i = 0; i < 8; ++i)
#pragma unroll
    for (int j = 0; j < 8; ++j) acc[i][j] = 0.f;

  for (int k0 = 0; k0 < K; k0 += 16) {
#pragma unroll
    for (int l = 0; l < 2; ++l) {
      const int idx = tid + l * 256;
      const int r = idx >> 2, c = (idx & 3) << 2;
      const float4 a = *(const float4*)&A[(size_t)(bm + r) * K + k0 + c];
      As[c + 0][r] = a.x; As[c + 1][r] = a.y; As[c + 2][r] = a.z; As[c + 3][r] = a.w;
    }
    if (!TRANSB) {
#pragma unroll
      for (int l = 0; l < 2; ++l) {
        const int idx = tid + l * 256;
        const int r = idx >> 5, c = (idx & 31) << 2;
        *(float4*)&Bs[r][c] = *(const float4*)&B[(size_t)(k0 + r) * N + bn + c];
      }
    } else {
#pragma unroll
      for (int l = 0; l < 2; ++l) {
        const int idx = tid + l * 256;
        const int r = idx >> 2, c = (idx & 3) << 2;
        const float4 bv = *(const float4*)&B[(size_t)(bn + r) * K + k0 + c];
        Bs[c + 0][r] = bv.x; Bs[c + 1][r] = bv.y; Bs[c + 2][r] = bv.z; Bs[c + 3][r] = bv.w;
      }
    }
    __syncthreads();
#pragma unroll
    for (int k = 0; k < 16; ++k) {
      float a[8], bb[8];
      *(float4*)&a[0]  = *(const float4*)&As[k][ty * 8];
      *(float4*)&a[4]  = *(const float4*)&As[k][ty * 8 + 4];
      *(float4*)&bb[0] = *(const float4*)&Bs[k][tx * 8];
      *(float4*)&bb[4] = *(const float4*)&Bs[k][tx * 8 + 4];
#pragma unroll
      for (int i = 0; i < 8; ++i)
#pragma unroll
        for (int j = 0; j < 8; ++j)
          acc[i][j] = fmaf(a[i], bb[j], acc[i][j]);
    }
    __syncthreads();
  }
#pragma unroll
  for (int i = 0; i < 8; ++i) {
    const size_t row = bm + ty * 8 + i;
#pragma unroll
    for (int u = 0; u < 2; ++u) {
      const size_t col = bn + tx * 8 + u * 4;
      float4 v = *(float4*)&acc[i][u * 4];
      if (RES) {
        const float4 r4 = *(const float4*)&Res[row * N + col];
        v.x += r4.x; v.y += r4.y; v.z += r4.z; v.w += r4.w;
      }
      if (CBF16) {
        u16* Cb = (u16*)Cv;
        ushort4 o4;
        o4.x = f2bf(v.x); o4.y = f2bf(v.y); o4.z = f2bf(v.z); o4.w = f2bf(v.w);
        *(ushort4*)&Cb[row * N + col] = o4;
      } else {
        float* Cf = (float*)Cv;
        *(float4*)&Cf[row * N + col] = v;
      }
    }
  }
}

// ---------------- e_s = (q + r_s_bias) . seg_mat[s], s in {0,1} ----------------
__global__ __launch_bounds__(256)
void seg_e_kernel(const u16* __restrict__ Qb, const float* __restrict__ rsb,
                  const float* __restrict__ segm, float* __restrict__ E) {
  const int gt = blockIdx.x * 256 + threadIdx.x;  // gt = (i*BSZ+b)*NHEAD + n
  const int n = gt & 15;
  const size_t base = (size_t)gt * HDIM;
  float e0 = 0.f, e1 = 0.f;
#pragma unroll
  for (int u8 = 0; u8 < 8; ++u8) {
    const uint4 qv = *(const uint4*)&Qb[base + u8 * 8];
    float qf[8];
    bf8_to_f(qv, qf);
#pragma unroll
    for (int w = 0; w < 8; ++w) {
      const int d = u8 * 8 + w;
      const float q = qf[w] + rsb[n * HDIM + d];
      e0 += q * segm[n * HDIM + d];
      e1 += q * segm[HIDN + n * HDIM + d];
    }
  }
  E[(size_t)gt * 2 + 0] = e0;
  E[(size_t)gt * 2 + 1] = e1;
}

// ---------------- fused attention: scores + rel-shift gather + seg + mask,
//                  online softmax, PV. One block = (b, n, 32 query rows). ----------
__global__ __launch_bounds__(256)
void attn_kernel(const u16* __restrict__ Qb, const u16* __restrict__ Kb,
                 const u16* __restrict__ Vb, const u16* __restrict__ Krb,
                 const float* __restrict__ E, const float* __restrict__ seg_e,
                 const float* __restrict__ mask, const float* __restrict__ rwb,
                 const float* __restrict__ rrb, float* __restrict__ AO) {
  __shared__ float qc[32 * 64];    // q + r_w_bias
  __shared__ float qr[32 * 64];    // q + r_r_bias
  __shared__ float KtF[64 * 64];   // K tile, XOR-swizzled float4 columns
  __shared__ float KrF[95 * 64];   // Kr window, XOR-swizzled
  __shared__ float P[32 * 64];     // probabilities tile
  const int b = blockIdx.z, n = blockIdx.y, i0 = blockIdx.x * 32;
  const int t = threadIdx.x, tj = t & 63, wv = t >> 6;

  {  // stage qc/qr: 32 rows x 8 bf16x8-units, one unit/thread
    const int r = t >> 3, u8 = t & 7;
    const uint4 qv = *(const uint4*)&Qb[((((size_t)(i0 + r)) * BSZ + b) * NHEAD + n) * HDIM + u8 * 8];
    float qf[8];
    bf8_to_f(qv, qf);
    const int d0 = u8 * 8;
#pragma unroll
    for (int w = 0; w < 8; ++w) {
      qc[r * 64 + d0 + w] = qf[w] + rwb[n * HDIM + d0 + w];
      qr[r * 64 + d0 + w] = qf[w] + rrb[n * HDIM + d0 + w];
    }
  }
  float e0v[8], e1v[8], mrun[8], lrun[8], acc[8];
#pragma unroll
  for (int r = 0; r < 8; ++r) {
    const size_t i = i0 + wv * 8 + r;
    const float2 ee = *(const float2*)&E[((i * BSZ + b) * NHEAD + n) * 2];
    e0v[r] = ee.x; e1v[r] = ee.y;
    mrun[r] = -3.0e38f; lrun[r] = 0.f; acc[r] = 0.f;
  }
  __syncthreads();

  for (int jb = 0; jb < I_LEN; jb += 64) {
    const int jrbase = jb + 481 - i0;  // Kr window start; rr = tj + 31 - i_loc
    // stage K tile (64 rows)
#pragma unroll
    for (int l = 0; l < 2; ++l) {
      const int idx = t + l * 256;
      const int r = idx >> 3, u8 = idx & 7;
      const uint4 kv = *(const uint4*)&Kb[((((size_t)(jb + r)) * BSZ + b) * NHEAD + n) * HDIM + u8 * 8];
      float kf[8];
      bf8_to_f(kv, kf);
      const int dq0 = u8 * 2;
      *(float4*)&KtF[(r * 16 + (dq0 ^ (r & 15))) * 4]       = make_float4(kf[0], kf[1], kf[2], kf[3]);
      *(float4*)&KtF[(r * 16 + ((dq0 + 1) ^ (r & 15))) * 4] = make_float4(kf[4], kf[5], kf[6], kf[7]);
    }
    // stage Kr window (95 rows)
#pragma unroll
    for (int l = 0; l < 3; ++l) {
      const int idx = t + l * 256;
      if (idx < 95 * 8) {
        const int r = idx >> 3, u8 = idx & 7;
        int pr = jrbase + r; if (pr > PLEN_ - 1) pr = PLEN_ - 1;  // tail rows unused
        const uint4 kv = *(const uint4*)&Krb[(((size_t)pr * BSZ + b) * NHEAD + n) * HDIM + u8 * 8];
        float kf[8];
        bf8_to_f(kv, kf);
        const int dq0 = u8 * 2;
        *(float4*)&KrF[(r * 16 + (dq0 ^ (r & 15))) * 4]       = make_float4(kf[0], kf[1], kf[2], kf[3]);
        *(float4*)&KrF[(r * 16 + ((dq0 + 1) ^ (r & 15))) * 4] = make_float4(kf[4], kf[5], kf[6], kf[7]);
      }
    }
    __syncthreads();

    float s[8];
#pragma unroll
    for (int r = 0; r < 8; ++r) s[r] = 0.f;
    const float4* qc4 = (const float4*)qc;
    const float4* qr4 = (const float4*)qr;
    const float4* Kt4 = (const float4*)KtF;
    const float4* Kr4 = (const float4*)KrF;
    // content scores: (q+rw) . K[j]
#pragma unroll
    for (int dq = 0; dq < 16; ++dq) {
      const float4 k4 = Kt4[tj * 16 + (dq ^ (tj & 15))];
#pragma unroll
      for (int r = 0; r < 8; ++r) {
        const float4 q4 = qc4[(wv * 8 + r) * 16 + dq];
        s[r] += q4.x * k4.x + q4.y * k4.y + q4.z * k4.z + q4.w * k4.w;
      }
    }
    // position scores: (q+rr) . Kr[j + 512 - i]   (rel_shift as gather)
#pragma unroll
    for (int r = 0; r < 8; ++r) {
      const int rr = tj + 31 - (wv * 8 + r);
      float sr = 0.f;
#pragma unroll
      for (int dq = 0; dq < 16; ++dq) {
        const float4 k4 = Kr4[rr * 16 + (dq ^ (rr & 15))];
        const float4 q4 = qr4[(wv * 8 + r) * 16 + dq];
        sr += q4.x * k4.x + q4.y * k4.y + q4.z * k4.z + q4.w * k4.w;
      }
      s[r] += sr;
    }
    const int j = jb + tj;
#pragma unroll
    for (int r = 0; r < 8; ++r) {
      const size_t i = i0 + wv * 8 + r;
      const float2 se = *(const float2*)&seg_e[((i * I_LEN + j) * BSZ + b) * 2];
      const float mk = mask[(i * I_LEN + j) * BSZ + b];
      const float sc = (s[r] + se.x * e0v[r] + se.y * e1v[r]) * SCALE_F - BIGNUM * mk;
      // online softmax (row lives entirely in this wave's 64 lanes)
      float tm = sc;
#pragma unroll
      for (int o = 32; o >= 1; o >>= 1) tm = fmaxf(tm, __shfl_xor(tm, o));
      const float mn = fmaxf(mrun[r], tm);
      const float p = __expf(sc - mn);
      float ps = p;
#pragma unroll
      for (int o = 32; o >= 1; o >>= 1) ps += __shfl_xor(ps, o);
      const float f = __expf(mrun[r] - mn);
      lrun[r] = lrun[r] * f + ps;
      mrun[r] = mn;
      acc[r] *= f;
      P[(wv * 8 + r) * 64 + tj] = p;
    }
    // PV: lane tj now indexes head-dim d; V reads are coalesced from global (L2-hot)
    const u16* Vg = &Vb[((((size_t)jb) * BSZ + b) * NHEAD + n) * HDIM + tj];
#pragma unroll
    for (int jj0 = 0; jj0 < 64; jj0 += 8) {
      float vv[8];
#pragma unroll
      for (int u = 0; u < 8; ++u)
        vv[u] = __uint_as_float(((u32)Vg[(size_t)(jj0 + u) * (BSZ * NHEAD * HDIM)]) << 16);
#pragma unroll
      for (int u = 0; u < 8; ++u)
#pragma unroll
        for (int r = 0; r < 8; ++r)
          acc[r] = fmaf(P[(wv * 8 + r) * 64 + jj0 + u], vv[u], acc[r]);
    }
    __syncthreads();
  }
#pragma unroll
  for (int r = 0; r < 8; ++r) {
    const size_t i = i0 + wv * 8 + r;
    AO[((i * BSZ + b) * NHEAD + n) * HDIM + tj] = acc[r] / lrun[r];
  }
}

// ---------------- LayerNorm over HID=1024, one block per (i,b) row ----------------
__global__ __launch_bounds__(256)
void ln_kernel(const float* __restrict__ X, const float* __restrict__ gam,
               const float* __restrict__ bet, float* __restrict__ out) {
  const int row = blockIdx.x, t = threadIdx.x;
  const float4 x4 = *(const float4*)&X[(size_t)row * HIDN + t * 4];
  float s  = x4.x + x4.y + x4.z + x4.w;
  float sq = x4.x * x4.x + x4.y * x4.y + x4.z * x4.z + x4.w * x4.w;
#pragma unroll
  for (int o = 32; o >= 1; o >>= 1) { s += __shfl_xor(s, o); sq += __shfl_xor(sq, o); }
  __shared__ float red[8];
  const int wv = t >> 6;
  if ((t & 63) == 0) { red[wv * 2] = s; red[wv * 2 + 1] = sq; }
  __syncthreads();
  s  = red[0] + red[2] + red[4] + red[6];
  sq = red[1] + red[3] + red[5] + red[7];
  const float mu  = s * (1.f / HIDN);
  const float var = sq * (1.f / HIDN) - mu * mu;
  const float rs  = rsqrtf(var + LN_EPS);
  const float4 g4 = *(const float4*)&gam[t * 4];
  const float4 b4 = *(const float4*)&bet[t * 4];
  float4 o4;
  o4.x = (x4.x - mu) * rs * g4.x + b4.x;
  o4.y = (x4.y - mu) * rs * g4.y + b4.y;
  o4.z = (x4.z - mu) * rs * g4.z + b4.z;
  o4.w = (x4.w - mu) * rs * g4.w + b4.w;
  *(float4*)&out[(size_t)row * HIDN + t * 4] = o4;
}

extern "C" void kernel_launch(void* const* d_in, const int* in_sizes, int n_in,
                              void* d_out, int out_size, void* d_ws, size_t ws_size,
                              hipStream_t stream) {
  (void)in_sizes; (void)n_in; (void)out_size; (void)ws_size;
  const float* hidden = (const float*)d_in[0];
  const float* pos    = (const float*)d_in[1];
  const float* sege   = (const float*)d_in[2];
  const float* amask  = (const float*)d_in[3];
  const float* qw     = (const float*)d_in[4];
  const float* kw     = (const float*)d_in[5];
  const float* vw     = (const float*)d_in[6];
  const float* rw     = (const float*)d_in[7];
  const float* ow     = (const float*)d_in[8];
  const float* rwb    = (const float*)d_in[9];
  const float* rrb    = (const float*)d_in[10];
  const float* rsb    = (const float*)d_in[11];
  const float* segm   = (const float*)d_in[12];
  const float* gam    = (const float*)d_in[13];
  const float* bet    = (const float*)d_in[14];
  float* out = (float*)d_out;
  char* ws = (char*)d_ws;

  const size_t QE = (size_t)I_LEN * BSZ * HIDN;          // 4,194,304 elements
  u16*   Qb  = (u16*)(ws);                                // bf16, QE
  u16*   Kb  = (u16*)(ws + QE * 2);                       // bf16, QE
  u16*   Vb  = (u16*)(ws + QE * 4);                       // bf16, QE
  u16*   Krb = (u16*)(ws + QE * 6);                       // bf16, 2*QE
  float* AO  = (float*)(ws + QE * 10);                    // fp32, QE
  float* E   = (float*)(ws + QE * 14);                    // fp32, 131072
  float* X   = (float*)(ws);                              // fp32, QE — overlays Qb+Kb (done by then)

  sgemm128<false, false, true><<<dim3(8, 32), 256, 0, stream>>>(hidden, qw, nullptr, Qb);
  sgemm128<false, false, true><<<dim3(8, 32), 256, 0, stream>>>(hidden, kw, nullptr, Kb);
  sgemm128<false, false, true><<<dim3(8, 32), 256, 0, stream>>>(hidden, vw, nullptr, Vb);
  sgemm128<false, false, true><<<dim3(8, 64), 256, 0, stream>>>(pos,    rw, nullptr, Krb);
  seg_e_kernel<<<256, 256, 0, stream>>>(Qb, rsb, segm, E);
  attn_kernel<<<dim3(16, 16, 8), 256, 0, stream>>>(Qb, Kb, Vb, Krb, E, sege, amask, rwb, rrb, AO);
  sgemm128<true, true, false><<<dim3(8, 32), 256, 0, stream>>>(AO, ow, hidden, X);
  ln_kernel<<<4096, 256, 0, stream>>>(X, gam, bet, out);
}

// Round 2
// 918.436 us; speedup vs baseline: 4.4737x; 4.4737x over previous
//
#include <hip/hip_runtime.h>
#include <hip/hip_bf16.h>

#define I_LEN 512
#define BSZ   8
#define HIDN  1024
#define NHEAD 16
#define HDIM  64
#define PLEN_ 1024
#define SCALE_F 0.125f
#define BIGNUM 1e30f
#define LN_EPS 1e-5f

typedef unsigned int   u32;
typedef unsigned short u16;
typedef __attribute__((ext_vector_type(8))) short bf16x8;
typedef __attribute__((ext_vector_type(4))) float f32x4;

__device__ __forceinline__ float bflo(u32 w) { return __uint_as_float(w << 16); }
__device__ __forceinline__ float bfhi(u32 w) { return __uint_as_float(w & 0xffff0000u); }
__device__ __forceinline__ u16 f2bf(float x) {
  u32 u = __float_as_uint(x);
  return (u16)((u + 0x7fffu + ((u >> 16) & 1u)) >> 16);
}
__device__ __forceinline__ void bf8_to_f(const uint4 v, float* f) {
  f[0] = bflo(v.x); f[1] = bfhi(v.x);
  f[2] = bflo(v.y); f[3] = bfhi(v.y);
  f[4] = bflo(v.z); f[5] = bfhi(v.z);
  f[6] = bflo(v.w); f[7] = bfhi(v.w);
}

// ---------------- fp32 SGEMM 128x128x16, 256 thr, 8x8 microtile ----------------
template<bool TRANSB, bool RES, bool CBF16>
__global__ __launch_bounds__(256)
void sgemm128(const float* __restrict__ A, const float* __restrict__ B,
              const float* __restrict__ Res, void* __restrict__ Cv) {
  constexpr int K = 1024, N = 1024;
  __shared__ float As[16][132];
  __shared__ float Bs[16][132];
  const int bm = blockIdx.y * 128, bn = blockIdx.x * 128;
  const int tid = threadIdx.x;
  const int ty = tid >> 4, tx = tid & 15;
  float acc[8][8];
#pragma unroll
  for (int i = 0; i < 8; ++i)
#pragma unroll
    for (int j = 0; j < 8; ++j) acc[i][j] = 0.f;

  for (int k0 = 0; k0 < K; k0 += 16) {
#pragma unroll
    for (int l = 0; l < 2; ++l) {
      const int idx = tid + l * 256;
      const int r = idx >> 2, c = (idx & 3) << 2;
      const float4 a = *(const float4*)&A[(size_t)(bm + r) * K + k0 + c];
      As[c + 0][r] = a.x; As[c + 1][r] = a.y; As[c + 2][r] = a.z; As[c + 3][r] = a.w;
    }
    if (!TRANSB) {
#pragma unroll
      for (int l = 0; l < 2; ++l) {
        const int idx = tid + l * 256;
        const int r = idx >> 5, c = (idx & 31) << 2;
        *(float4*)&Bs[r][c] = *(const float4*)&B[(size_t)(k0 + r) * N + bn + c];
      }
    } else {
#pragma unroll
      for (int l = 0; l < 2; ++l) {
        const int idx = tid + l * 256;
        const int r = idx >> 2, c = (idx & 3) << 2;
        const float4 bv = *(const float4*)&B[(size_t)(bn + r) * K + k0 + c];
        Bs[c + 0][r] = bv.x; Bs[c + 1][r] = bv.y; Bs[c + 2][r] = bv.z; Bs[c + 3][r] = bv.w;
      }
    }
    __syncthreads();
#pragma unroll
    for (int k = 0; k < 16; ++k) {
      float a[8], bb[8];
      *(float4*)&a[0]  = *(const float4*)&As[k][ty * 8];
      *(float4*)&a[4]  = *(const float4*)&As[k][ty * 8 + 4];
      *(float4*)&bb[0] = *(const float4*)&Bs[k][tx * 8];
      *(float4*)&bb[4] = *(const float4*)&Bs[k][tx * 8 + 4];
#pragma unroll
      for (int i = 0; i < 8; ++i)
#pragma unroll
        for (int j = 0; j < 8; ++j)
          acc[i][j] = fmaf(a[i], bb[j], acc[i][j]);
    }
    __syncthreads();
  }
#pragma unroll
  for (int i = 0; i < 8; ++i) {
    const size_t row = bm + ty * 8 + i;
#pragma unroll
    for (int u = 0; u < 2; ++u) {
      const size_t col = bn + tx * 8 + u * 4;
      float4 v = *(float4*)&acc[i][u * 4];
      if (RES) {
        const float4 r4 = *(const float4*)&Res[row * N + col];
        v.x += r4.x; v.y += r4.y; v.z += r4.z; v.w += r4.w;
      }
      if (CBF16) {
        u16* Cb = (u16*)Cv;
        ushort4 o4;
        o4.x = f2bf(v.x); o4.y = f2bf(v.y); o4.z = f2bf(v.z); o4.w = f2bf(v.w);
        *(ushort4*)&Cb[row * N + col] = o4;
      } else {
        float* Cf = (float*)Cv;
        *(float4*)&Cf[row * N + col] = v;
      }
    }
  }
}

// ---------------- V transpose: Vb[i][b][n][d] -> Vt[b][n][d][i] (bf16) ----------------
__global__ __launch_bounds__(256)
void vtrans_kernel(const u16* __restrict__ Vb, u16* __restrict__ Vt) {
  __shared__ u16 tile[64][80];  // stride 80 u16 = 160B (16B aligned, banks spread)
  const int bn = blockIdx.x;    // b*16+n
  const int i0 = blockIdx.y * 64;
  const int t = threadIdx.x;
  {
    const int il = t >> 2, d0 = (t & 3) * 16;
    const uint4 v0 = *(const uint4*)&Vb[(size_t)(i0 + il) * 8192 + bn * 64 + d0];
    const uint4 v1 = *(const uint4*)&Vb[(size_t)(i0 + il) * 8192 + bn * 64 + d0 + 8];
    *(uint4*)&tile[il][d0] = v0;
    *(uint4*)&tile[il][d0 + 8] = v1;
  }
  __syncthreads();
  const int d = t >> 2, ic = (t & 3) * 16;
  union { u16 us[16]; uint4 q[2]; } o;
#pragma unroll
  for (int e = 0; e < 16; ++e) o.us[e] = tile[ic + e][d];
  uint4* dst = (uint4*)&Vt[((size_t)bn * 64 + d) * 512 + i0 + ic];
  dst[0] = o.q[0]; dst[1] = o.q[1];
}

// ---------------- e_s = (q + r_s_bias) . seg_mat[s], s in {0,1} ----------------
__global__ __launch_bounds__(256)
void seg_e_kernel(const u16* __restrict__ Qb, const float* __restrict__ rsb,
                  const float* __restrict__ segm, float* __restrict__ E) {
  const int gt = blockIdx.x * 256 + threadIdx.x;  // gt = (i*BSZ+b)*NHEAD + n
  const int n = gt & 15;
  const size_t base = (size_t)gt * HDIM;
  float e0 = 0.f, e1 = 0.f;
#pragma unroll
  for (int u8 = 0; u8 < 8; ++u8) {
    const uint4 qv = *(const uint4*)&Qb[base + u8 * 8];
    float qf[8];
    bf8_to_f(qv, qf);
#pragma unroll
    for (int w = 0; w < 8; ++w) {
      const int d = u8 * 8 + w;
      const float q = qf[w] + rsb[n * HDIM + d];
      e0 += q * segm[n * HDIM + d];
      e1 += q * segm[HIDN + n * HDIM + d];
    }
  }
  E[(size_t)gt * 2 + 0] = e0;
  E[(size_t)gt * 2 + 1] = e1;
}

// ---------------- MFMA fused attention ----------------
// Block = (b,n, 64 i-rows); 4 waves, each owns 16 i-rows, full j sweep.
// No __syncthreads in the j-loop: per-wave private LDS slices only.
// mfma_f32_16x16x32_bf16 layouts:
//   A: row=lane&15, k=(lane>>4)*8+e (8 consecutive bf16 -> one uint4 load)
//   B: col=lane&15, k=(lane>>4)*8+e
//   C/D: col=lane&15, row=(lane>>4)*4+reg   [m89-verified]
__global__ __launch_bounds__(256)
void attn_mfma(const u16* __restrict__ Qb, const u16* __restrict__ Kb,
               const u16* __restrict__ Vt, const u16* __restrict__ Krb,
               const float* __restrict__ E, const float* __restrict__ sege,
               const float* __restrict__ amask, const float* __restrict__ rwb,
               const float* __restrict__ rrb, float* __restrict__ AO) {
  __shared__ float Tl[4][16 * 83];  // bd window, stride 83: write ~2-way, shifted read 2-way
  __shared__ u16   Pl[4][16 * 64];  // P tile, XOR-swizzled for conflict-free b128 read
  const int bn = blockIdx.x, b = bn >> 4, n = bn & 15;
  const int i0 = blockIdx.y * 64;
  const int t = threadIdx.x, wv = t >> 6, lane = t & 63;
  const int l15 = lane & 15, g = lane >> 4;
  const int irow0 = i0 + wv * 16;       // first global i-row of this wave
  float* Tw = Tl[wv];
  u16*   Pw = Pl[wv];
  const int bn64 = bn * 64;

  // A-fragments of (q + r_w_bias) and (q + r_r_bias), kept resident
  bf16x8 qcf[2], qrf[2];
#pragma unroll
  for (int h = 0; h < 2; ++h) {
    const int d0 = 32 * h + g * 8;
    const uint4 qv = *(const uint4*)&Qb[(size_t)(irow0 + l15) * 8192 + bn64 + d0];
    float qf[8]; bf8_to_f(qv, qf);
    union { u16 us[8]; bf16x8 v; } ua, ub;
#pragma unroll
    for (int w = 0; w < 8; ++w) {
      ua.us[w] = f2bf(qf[w] + rwb[n * HDIM + d0 + w]);
      ub.us[w] = f2bf(qf[w] + rrb[n * HDIM + d0 + w]);
    }
    qcf[h] = ua.v; qrf[h] = ub.v;
  }

  float e0v[4], e1v[4], mrun[4], lrun[4];
  f32x4 accO[4];
#pragma unroll
  for (int r = 0; r < 4; ++r) {
    const int i = irow0 + 4 * g + r;
    const float2 ee = *(const float2*)&E[((size_t)(i * BSZ + b) * NHEAD + n) * 2];
    e0v[r] = ee.x; e1v[r] = ee.y;
    mrun[r] = -3.0e38f; lrun[r] = 0.f;
  }
#pragma unroll
  for (int c = 0; c < 4; ++c) accO[c] = (f32x4){0.f, 0.f, 0.f, 0.f};

  for (int jb = 0; jb < I_LEN; jb += 64) {
    // ---- ac scores: S = (q+rw) . K^T, 4 j-tiles x K=64 ----
    f32x4 S[4];
#pragma unroll
    for (int c = 0; c < 4; ++c) S[c] = (f32x4){0.f, 0.f, 0.f, 0.f};
#pragma unroll
    for (int c = 0; c < 4; ++c) {
      const u16* kp = &Kb[(size_t)(jb + 16 * c + l15) * 8192 + bn64 + g * 8];
      S[c] = __builtin_amdgcn_mfma_f32_16x16x32_bf16(qcf[0], *(const bf16x8*)kp, S[c], 0, 0, 0);
      S[c] = __builtin_amdgcn_mfma_f32_16x16x32_bf16(qcf[1], *(const bf16x8*)(kp + 32), S[c], 0, 0, 0);
    }
    // ---- bd window: T[ii][u-ubase] = (q+rr) . Kr_u, 5 u-tiles ----
    const int ubase = jb + 497 - irow0;   // col = jj + 15 - ii, in [0,78]
    f32x4 T[5];
#pragma unroll
    for (int c = 0; c < 5; ++c) T[c] = (f32x4){0.f, 0.f, 0.f, 0.f};
#pragma unroll
    for (int c = 0; c < 5; ++c) {
      int ur = ubase + 16 * c + l15;
      ur = ur < (PLEN_ - 1) ? ur : (PLEN_ - 1);   // col 79 is never read; clamp keeps load in-bounds
      const u16* kp = &Krb[(size_t)ur * 8192 + bn64 + g * 8];
      T[c] = __builtin_amdgcn_mfma_f32_16x16x32_bf16(qrf[0], *(const bf16x8*)kp, T[c], 0, 0, 0);
      T[c] = __builtin_amdgcn_mfma_f32_16x16x32_bf16(qrf[1], *(const bf16x8*)(kp + 32), T[c], 0, 0, 0);
    }
    // park T in per-wave LDS slice (C-layout write)
#pragma unroll
    for (int c = 0; c < 5; ++c)
#pragma unroll
      for (int r = 0; r < 4; ++r)
        Tw[(4 * g + r) * 83 + 16 * c + l15] = T[c][r];
    // ---- assemble scores: +bd(shifted) +seg +mask ----
#pragma unroll
    for (int c = 0; c < 4; ++c) {
      const int j = jb + 16 * c + l15;
#pragma unroll
      for (int r = 0; r < 4; ++r) {
        const int ii = 4 * g + r;
        const float bd = Tw[ii * 82 + 15 + 16 * c + l15];   // = Tw[ii*83 + (jj+15-ii)]
        const size_t ijb = ((size_t)(irow0 + ii) * I_LEN + j) * BSZ + b;
        const float2 se = *(const float2*)&sege[ijb * 2];
        const float mk = amask[ijb];
        S[c][r] = (S[c][r] + bd + se.x * e0v[r] + se.y * e1v[r]) * SCALE_F - BIGNUM * mk;
      }
    }
    // ---- online softmax: each lane owns rows 4g+r, row spread over 16 lanes x 4 tiles ----
#pragma unroll
    for (int r = 0; r < 4; ++r) {
      float tm = fmaxf(fmaxf(S[0][r], S[1][r]), fmaxf(S[2][r], S[3][r]));
#pragma unroll
      for (int o = 1; o < 16; o <<= 1) tm = fmaxf(tm, __shfl_xor(tm, o));
      const float mn = fmaxf(mrun[r], tm);
      const float f = __expf(mrun[r] - mn);
      mrun[r] = mn;
      float ps = 0.f;
#pragma unroll
      for (int c = 0; c < 4; ++c) {
        const float p = __expf(S[c][r] - mn);
        S[c][r] = p;
        ps += p;
        accO[c][r] = accO[c][r] * f;
      }
#pragma unroll
      for (int o = 1; o < 16; o <<= 1) ps += __shfl_xor(ps, o);
      lrun[r] = lrun[r] * f + ps;
    }
    // ---- P -> LDS (bf16, XOR swizzle), re-read as A-fragments ----
#pragma unroll
    for (int c = 0; c < 4; ++c)
#pragma unroll
      for (int r = 0; r < 4; ++r) {
        const int ii = 4 * g + r;
        Pw[ii * 64 + ((16 * c + l15) ^ ((ii & 7) << 3))] = f2bf(S[c][r]);
      }
    const bf16x8 pa0 = *(const bf16x8*)&Pw[l15 * 64 + ((g * 8) ^ ((l15 & 7) << 3))];
    const bf16x8 pa1 = *(const bf16x8*)&Pw[l15 * 64 + ((32 + g * 8) ^ ((l15 & 7) << 3))];
    // ---- PV: accO[c] += P . V, V B-frags contiguous from Vt ----
#pragma unroll
    for (int c = 0; c < 4; ++c) {
      const u16* vp = &Vt[((size_t)bn64 + 16 * c + l15) * 512 + jb + g * 8];
      accO[c] = __builtin_amdgcn_mfma_f32_16x16x32_bf16(pa0, *(const bf16x8*)vp, accO[c], 0, 0, 0);
      accO[c] = __builtin_amdgcn_mfma_f32_16x16x32_bf16(pa1, *(const bf16x8*)(vp + 32), accO[c], 0, 0, 0);
    }
  }
  // ---- epilogue: divide by denom, write AO fp32 ----
#pragma unroll
  for (int c = 0; c < 4; ++c)
#pragma unroll
    for (int r = 0; r < 4; ++r) {
      const int ii = 4 * g + r;
      AO[(size_t)(irow0 + ii) * 8192 + bn64 + 16 * c + l15] = accO[c][r] / lrun[r];
    }
}

// ---------------- LayerNorm over HID=1024, one block per (i,b) row ----------------
__global__ __launch_bounds__(256)
void ln_kernel(const float* __restrict__ X, const float* __restrict__ gam,
               const float* __restrict__ bet, float* __restrict__ out) {
  const int row = blockIdx.x, t = threadIdx.x;
  const float4 x4 = *(const float4*)&X[(size_t)row * HIDN + t * 4];
  float s  = x4.x + x4.y + x4.z + x4.w;
  float sq = x4.x * x4.x + x4.y * x4.y + x4.z * x4.z + x4.w * x4.w;
#pragma unroll
  for (int o = 32; o >= 1; o >>= 1) { s += __shfl_xor(s, o); sq += __shfl_xor(sq, o); }
  __shared__ float red[8];
  const int wv = t >> 6;
  if ((t & 63) == 0) { red[wv * 2] = s; red[wv * 2 + 1] = sq; }
  __syncthreads();
  s  = red[0] + red[2] + red[4] + red[6];
  sq = red[1] + red[3] + red[5] + red[7];
  const float mu  = s * (1.f / HIDN);
  const float var = sq * (1.f / HIDN) - mu * mu;
  const float rs  = rsqrtf(var + LN_EPS);
  const float4 g4 = *(const float4*)&gam[t * 4];
  const float4 b4 = *(const float4*)&bet[t * 4];
  float4 o4;
  o4.x = (x4.x - mu) * rs * g4.x + b4.x;
  o4.y = (x4.y - mu) * rs * g4.y + b4.y;
  o4.z = (x4.z - mu) * rs * g4.z + b4.z;
  o4.w = (x4.w - mu) * rs * g4.w + b4.w;
  *(float4*)&out[(size_t)row * HIDN + t * 4] = o4;
}

extern "C" void kernel_launch(void* const* d_in, const int* in_sizes, int n_in,
                              void* d_out, int out_size, void* d_ws, size_t ws_size,
                              hipStream_t stream) {
  (void)in_sizes; (void)n_in; (void)out_size; (void)ws_size;
  const float* hidden = (const float*)d_in[0];
  const float* pos    = (const float*)d_in[1];
  const float* sege   = (const float*)d_in[2];
  const float* amask  = (const float*)d_in[3];
  const float* qw     = (const float*)d_in[4];
  const float* kw     = (const float*)d_in[5];
  const float* vw     = (const float*)d_in[6];
  const float* rw     = (const float*)d_in[7];
  const float* ow     = (const float*)d_in[8];
  const float* rwb    = (const float*)d_in[9];
  const float* rrb    = (const float*)d_in[10];
  const float* rsb    = (const float*)d_in[11];
  const float* segm   = (const float*)d_in[12];
  const float* gam    = (const float*)d_in[13];
  const float* bet    = (const float*)d_in[14];
  float* out = (float*)d_out;
  char* ws = (char*)d_ws;

  const size_t QE = (size_t)I_LEN * BSZ * HIDN;  // 4,194,304
  // byte layout (max 67.1 MB):
  u16*   Qb  = (u16*)(ws);              // [0,      2QE)
  u16*   Kb  = (u16*)(ws + QE * 2);     // [2QE,    4QE)
  u16*   Vb  = (u16*)(ws + QE * 4);     // [4QE,    6QE)   dead after vtrans
  u16*   Krb = (u16*)(ws + QE * 6);     // [6QE,   10QE)
  u16*   Vt  = (u16*)(ws + QE * 10);    // [10QE,  12QE)
  float* AO  = (float*)(ws + QE * 12);  // [12QE,  16QE)
  float* E   = (float*)(ws + QE * 4);   // overlays dead Vb (seg_e runs after vtrans)
  float* X   = (float*)(ws);            // overlays Qb+Kb (dead after attn)

  sgemm128<false, false, true><<<dim3(8, 32), 256, 0, stream>>>(hidden, qw, nullptr, Qb);
  sgemm128<false, false, true><<<dim3(8, 32), 256, 0, stream>>>(hidden, kw, nullptr, Kb);
  sgemm128<false, false, true><<<dim3(8, 32), 256, 0, stream>>>(hidden, vw, nullptr, Vb);
  sgemm128<false, false, true><<<dim3(8, 64), 256, 0, stream>>>(pos,    rw, nullptr, Krb);
  vtrans_kernel<<<dim3(128, 8), 256, 0, stream>>>(Vb, Vt);
  seg_e_kernel<<<256, 256, 0, stream>>>(Qb, rsb, segm, E);
  attn_mfma<<<dim3(128, 8), 256, 0, stream>>>(Qb, Kb, Vt, Krb, E, sege, amask, rwb, rrb, AO);
  sgemm128<true, true, false><<<dim3(8, 32), 256, 0, stream>>>(AO, ow, hidden, X);
  ln_kernel<<<4096, 256, 0, stream>>>(X, gam, bet, out);
}

// Round 3
// 348.500 us; speedup vs baseline: 11.7900x; 2.6354x over previous
//
#include <hip/hip_runtime.h>
#include <hip/hip_bf16.h>

#define I_LEN 512
#define BSZ   8
#define HIDN  1024
#define NHEAD 16
#define HDIM  64
#define PLEN_ 1024
#define SCALE_F 0.125f
#define BIGNUM 1e30f
#define LN_EPS 1e-5f

typedef unsigned int   u32;
typedef unsigned short u16;
typedef __attribute__((ext_vector_type(8))) short bf16x8;
typedef __attribute__((ext_vector_type(4))) float f32x4;

__device__ __forceinline__ float bflo(u32 w) { return __uint_as_float(w << 16); }
__device__ __forceinline__ float bfhi(u32 w) { return __uint_as_float(w & 0xffff0000u); }
__device__ __forceinline__ u16 f2bf(float x) {
  u32 u = __float_as_uint(x);
  return (u16)((u + 0x7fffu + ((u >> 16) & 1u)) >> 16);
}
__device__ __forceinline__ void bf8_to_f(const uint4 v, float* f) {
  f[0] = bflo(v.x); f[1] = bfhi(v.x);
  f[2] = bflo(v.y); f[3] = bfhi(v.y);
  f[4] = bflo(v.z); f[5] = bfhi(v.z);
  f[6] = bflo(v.w); f[7] = bfhi(v.w);
}

#define GLOAD_LDS16(gp, lp) __builtin_amdgcn_global_load_lds( \
    (const __attribute__((address_space(1))) void*)(gp),      \
    (__attribute__((address_space(3))) void*)(lp), 16, 0, 0)

// ---------------- bf16 MFMA GEMM: C[M][1024] = A[M][1024] . Bt[1024(outcol)][1024(k)]^T ----
// 128x128 tile, BK=64, 4 waves (2x2), 4x4 16x16x32 fragments per wave.
// LDS tiles XOR-swizzled (16B unit ^= row&7); A either fp32 (reg-staged+cvt) or bf16
// (global_load_lds w/ pre-swizzled source). z selects among up to 3 B/C pairs.
template<bool AF32, bool RES, bool OUTF32>
__global__ __launch_bounds__(256)
void gemm_bt(const void* __restrict__ Av, const u16* __restrict__ B0,
             const u16* __restrict__ B1, const u16* __restrict__ B2,
             void* __restrict__ C0, void* __restrict__ C1, void* __restrict__ C2,
             const float* __restrict__ Res) {
  constexpr int K = 1024;
  __shared__ u16 As[128 * 64];
  __shared__ u16 Bs[128 * 64];
  const int z = blockIdx.z;
  const u16* Bt = (z == 0) ? B0 : ((z == 1) ? B1 : B2);
  void* Cv = (z == 0) ? C0 : ((z == 1) ? C1 : C2);
  const int bm = blockIdx.y * 128, bn = blockIdx.x * 128;
  const int tid = threadIdx.x, wv = tid >> 6, lane = tid & 63;
  const int l15 = lane & 15, g = lane >> 4;
  const int wr = wv >> 1, wc = wv & 1;

  f32x4 acc[4][4];
#pragma unroll
  for (int m = 0; m < 4; ++m)
#pragma unroll
    for (int n = 0; n < 4; ++n) acc[m][n] = (f32x4){0.f, 0.f, 0.f, 0.f};

  for (int k0 = 0; k0 < K; k0 += 64) {
    // ---- stage B tile (async direct-to-LDS, source pre-swizzled) ----
#pragma unroll
    for (int p = 0; p < 4; ++p) {
      const int unit = (wv * 4 + p) * 64 + lane;
      const int row = unit >> 3, up = unit & 7, c = up ^ (row & 7);
      GLOAD_LDS16(&Bt[(size_t)(bn + row) * K + k0 + c * 8], &Bs[unit * 8]);
    }
    // ---- stage A tile ----
    if (AF32) {
      const float* A = (const float*)Av;
#pragma unroll
      for (int p = 0; p < 4; ++p) {
        const int unit = p * 256 + tid;
        const int row = unit >> 3, up = unit & 7, c = up ^ (row & 7);
        const float* src = &A[(size_t)(bm + row) * K + k0 + c * 8];
        const float4 f0 = *(const float4*)src;
        const float4 f1 = *(const float4*)(src + 4);
        ushort4 h0, h1;
        h0.x = f2bf(f0.x); h0.y = f2bf(f0.y); h0.z = f2bf(f0.z); h0.w = f2bf(f0.w);
        h1.x = f2bf(f1.x); h1.y = f2bf(f1.y); h1.z = f2bf(f1.z); h1.w = f2bf(f1.w);
        *(ushort4*)&As[unit * 8] = h0;
        *(ushort4*)&As[unit * 8 + 4] = h1;
      }
    } else {
      const u16* A = (const u16*)Av;
#pragma unroll
      for (int p = 0; p < 4; ++p) {
        const int unit = (wv * 4 + p) * 64 + lane;
        const int row = unit >> 3, up = unit & 7, c = up ^ (row & 7);
        GLOAD_LDS16(&A[(size_t)(bm + row) * K + k0 + c * 8], &As[unit * 8]);
      }
    }
    __syncthreads();
    // ---- compute: 2 K-halves x 16 MFMA ----
#pragma unroll
    for (int h = 0; h < 2; ++h) {
      bf16x8 af[4], bfv[4];
#pragma unroll
      for (int m = 0; m < 4; ++m) {
        const int row = wr * 64 + m * 16 + l15;
        af[m] = *(const bf16x8*)&As[row * 64 + ((h * 4 + g) ^ (row & 7)) * 8];
      }
#pragma unroll
      for (int n = 0; n < 4; ++n) {
        const int col = wc * 64 + n * 16 + l15;
        bfv[n] = *(const bf16x8*)&Bs[col * 64 + ((h * 4 + g) ^ (col & 7)) * 8];
      }
#pragma unroll
      for (int m = 0; m < 4; ++m)
#pragma unroll
        for (int n = 0; n < 4; ++n)
          acc[m][n] = __builtin_amdgcn_mfma_f32_16x16x32_bf16(af[m], bfv[n], acc[m][n], 0, 0, 0);
    }
    __syncthreads();
  }
  // ---- epilogue: C/D layout col=l15, row=g*4+r ----
#pragma unroll
  for (int m = 0; m < 4; ++m) {
    const int row0 = bm + wr * 64 + m * 16 + g * 4;
#pragma unroll
    for (int n = 0; n < 4; ++n) {
      const int col = bn + wc * 64 + n * 16 + l15;
#pragma unroll
      for (int r = 0; r < 4; ++r) {
        float v = acc[m][n][r];
        if (RES) v += Res[(size_t)(row0 + r) * 1024 + col];
        if (OUTF32) ((float*)Cv)[(size_t)(row0 + r) * 1024 + col] = v;
        else        ((u16*)Cv)[(size_t)(row0 + r) * 1024 + col] = f2bf(v);
      }
    }
  }
}

// ---------------- weight transpose+cvt: W[h][nd] f32 -> T[nd][h] bf16 ----------------
__global__ __launch_bounds__(256)
void wtrans_kernel(const float* __restrict__ W0, const float* __restrict__ W1,
                   const float* __restrict__ W2, const float* __restrict__ W3,
                   u16* __restrict__ T0, u16* __restrict__ T1,
                   u16* __restrict__ T2, u16* __restrict__ T3) {
  __shared__ u16 tile[64][72];
  const int z = blockIdx.z;
  const float* W = (z == 0) ? W0 : ((z == 1) ? W1 : ((z == 2) ? W2 : W3));
  u16* T = (z == 0) ? T0 : ((z == 1) ? T1 : ((z == 2) ? T2 : T3));
  const int h0 = blockIdx.y * 64, nd0 = blockIdx.x * 64;
  const int t = threadIdx.x;
  {
    const int hr = t >> 2, c0 = (t & 3) * 16;
#pragma unroll
    for (int q = 0; q < 4; ++q) {
      const float4 f = *(const float4*)&W[(size_t)(h0 + hr) * 1024 + nd0 + c0 + q * 4];
      tile[hr][c0 + q * 4 + 0] = f2bf(f.x);
      tile[hr][c0 + q * 4 + 1] = f2bf(f.y);
      tile[hr][c0 + q * 4 + 2] = f2bf(f.z);
      tile[hr][c0 + q * 4 + 3] = f2bf(f.w);
    }
  }
  __syncthreads();
  const int ndr = t >> 2, hc0 = (t & 3) * 16;
  union { u16 us[16]; uint4 qv[2]; } o;
#pragma unroll
  for (int e = 0; e < 16; ++e) o.us[e] = tile[hc0 + e][ndr];
  uint4* dst = (uint4*)&T[(size_t)(nd0 + ndr) * 1024 + h0 + hc0];
  dst[0] = o.qv[0]; dst[1] = o.qv[1];
}

// ---------------- f32 -> bf16 convert (ow) ----------------
__global__ __launch_bounds__(256)
void cvt_bf16_kernel(const float* __restrict__ in, u16* __restrict__ out) {
  const size_t i = ((size_t)blockIdx.x * 256 + threadIdx.x) * 8;
  const float4 a = *(const float4*)&in[i];
  const float4 b = *(const float4*)&in[i + 4];
  ushort4 o0, o1;
  o0.x = f2bf(a.x); o0.y = f2bf(a.y); o0.z = f2bf(a.z); o0.w = f2bf(a.w);
  o1.x = f2bf(b.x); o1.y = f2bf(b.y); o1.z = f2bf(b.z); o1.w = f2bf(b.w);
  *(ushort4*)&out[i] = o0;
  *(ushort4*)&out[i + 4] = o1;
}

// ---------------- V transpose: Vb[i][b][n][d] -> Vt[b][n][d][i] (bf16) ----------------
__global__ __launch_bounds__(256)
void vtrans_kernel(const u16* __restrict__ Vb, u16* __restrict__ Vt) {
  __shared__ u16 tile[64][80];
  const int bn = blockIdx.x;
  const int i0 = blockIdx.y * 64;
  const int t = threadIdx.x;
  {
    const int il = t >> 2, d0 = (t & 3) * 16;
    const uint4 v0 = *(const uint4*)&Vb[(size_t)(i0 + il) * 8192 + bn * 64 + d0];
    const uint4 v1 = *(const uint4*)&Vb[(size_t)(i0 + il) * 8192 + bn * 64 + d0 + 8];
    *(uint4*)&tile[il][d0] = v0;
    *(uint4*)&tile[il][d0 + 8] = v1;
  }
  __syncthreads();
  const int d = t >> 2, ic = (t & 3) * 16;
  union { u16 us[16]; uint4 q[2]; } o;
#pragma unroll
  for (int e = 0; e < 16; ++e) o.us[e] = tile[ic + e][d];
  uint4* dst = (uint4*)&Vt[((size_t)bn * 64 + d) * 512 + i0 + ic];
  dst[0] = o.q[0]; dst[1] = o.q[1];
}

// ---------------- e_s = (q + r_s_bias) . seg_mat[s], s in {0,1} ----------------
__global__ __launch_bounds__(256)
void seg_e_kernel(const u16* __restrict__ Qb, const float* __restrict__ rsb,
                  const float* __restrict__ segm, float* __restrict__ E) {
  const int gt = blockIdx.x * 256 + threadIdx.x;
  const int n = gt & 15;
  const size_t base = (size_t)gt * HDIM;
  float e0 = 0.f, e1 = 0.f;
#pragma unroll
  for (int u8 = 0; u8 < 8; ++u8) {
    const uint4 qv = *(const uint4*)&Qb[base + u8 * 8];
    float qf[8];
    bf8_to_f(qv, qf);
#pragma unroll
    for (int w = 0; w < 8; ++w) {
      const int d = u8 * 8 + w;
      const float q = qf[w] + rsb[n * HDIM + d];
      e0 += q * segm[n * HDIM + d];
      e1 += q * segm[HIDN + n * HDIM + d];
    }
  }
  E[(size_t)gt * 2 + 0] = e0;
  E[(size_t)gt * 2 + 1] = e1;
}

// ---------------- MFMA fused attention (unchanged core; AO now bf16) ----------------
__global__ __launch_bounds__(256)
void attn_mfma(const u16* __restrict__ Qb, const u16* __restrict__ Kb,
               const u16* __restrict__ Vt, const u16* __restrict__ Krb,
               const float* __restrict__ E, const float* __restrict__ sege,
               const float* __restrict__ amask, const float* __restrict__ rwb,
               const float* __restrict__ rrb, u16* __restrict__ AOb) {
  __shared__ float Tl[4][16 * 83];
  __shared__ u16   Pl[4][16 * 64];
  const int bn = blockIdx.x, b = bn >> 4, n = bn & 15;
  const int i0 = blockIdx.y * 64;
  const int t = threadIdx.x, wv = t >> 6, lane = t & 63;
  const int l15 = lane & 15, g = lane >> 4;
  const int irow0 = i0 + wv * 16;
  float* Tw = Tl[wv];
  u16*   Pw = Pl[wv];
  const int bn64 = bn * 64;

  bf16x8 qcf[2], qrf[2];
#pragma unroll
  for (int h = 0; h < 2; ++h) {
    const int d0 = 32 * h + g * 8;
    const uint4 qv = *(const uint4*)&Qb[(size_t)(irow0 + l15) * 8192 + bn64 + d0];
    float qf[8]; bf8_to_f(qv, qf);
    union { u16 us[8]; bf16x8 v; } ua, ub;
#pragma unroll
    for (int w = 0; w < 8; ++w) {
      ua.us[w] = f2bf(qf[w] + rwb[n * HDIM + d0 + w]);
      ub.us[w] = f2bf(qf[w] + rrb[n * HDIM + d0 + w]);
    }
    qcf[h] = ua.v; qrf[h] = ub.v;
  }

  float e0v[4], e1v[4], mrun[4], lrun[4];
  f32x4 accO[4];
#pragma unroll
  for (int r = 0; r < 4; ++r) {
    const int i = irow0 + 4 * g + r;
    const float2 ee = *(const float2*)&E[((size_t)(i * BSZ + b) * NHEAD + n) * 2];
    e0v[r] = ee.x; e1v[r] = ee.y;
    mrun[r] = -3.0e38f; lrun[r] = 0.f;
  }
#pragma unroll
  for (int c = 0; c < 4; ++c) accO[c] = (f32x4){0.f, 0.f, 0.f, 0.f};

  for (int jb = 0; jb < I_LEN; jb += 64) {
    f32x4 S[4];
#pragma unroll
    for (int c = 0; c < 4; ++c) S[c] = (f32x4){0.f, 0.f, 0.f, 0.f};
#pragma unroll
    for (int c = 0; c < 4; ++c) {
      const u16* kp = &Kb[(size_t)(jb + 16 * c + l15) * 8192 + bn64 + g * 8];
      S[c] = __builtin_amdgcn_mfma_f32_16x16x32_bf16(qcf[0], *(const bf16x8*)kp, S[c], 0, 0, 0);
      S[c] = __builtin_amdgcn_mfma_f32_16x16x32_bf16(qcf[1], *(const bf16x8*)(kp + 32), S[c], 0, 0, 0);
    }
    const int ubase = jb + 497 - irow0;
    f32x4 T[5];
#pragma unroll
    for (int c = 0; c < 5; ++c) T[c] = (f32x4){0.f, 0.f, 0.f, 0.f};
#pragma unroll
    for (int c = 0; c < 5; ++c) {
      int ur = ubase + 16 * c + l15;
      ur = ur < (PLEN_ - 1) ? ur : (PLEN_ - 1);
      const u16* kp = &Krb[(size_t)ur * 8192 + bn64 + g * 8];
      T[c] = __builtin_amdgcn_mfma_f32_16x16x32_bf16(qrf[0], *(const bf16x8*)kp, T[c], 0, 0, 0);
      T[c] = __builtin_amdgcn_mfma_f32_16x16x32_bf16(qrf[1], *(const bf16x8*)(kp + 32), T[c], 0, 0, 0);
    }
#pragma unroll
    for (int c = 0; c < 5; ++c)
#pragma unroll
      for (int r = 0; r < 4; ++r)
        Tw[(4 * g + r) * 83 + 16 * c + l15] = T[c][r];
#pragma unroll
    for (int c = 0; c < 4; ++c) {
      const int j = jb + 16 * c + l15;
#pragma unroll
      for (int r = 0; r < 4; ++r) {
        const int ii = 4 * g + r;
        const float bd = Tw[ii * 82 + 15 + 16 * c + l15];
        const size_t ijb = ((size_t)(irow0 + ii) * I_LEN + j) * BSZ + b;
        const float2 se = *(const float2*)&sege[ijb * 2];
        const float mk = amask[ijb];
        S[c][r] = (S[c][r] + bd + se.x * e0v[r] + se.y * e1v[r]) * SCALE_F - BIGNUM * mk;
      }
    }
#pragma unroll
    for (int r = 0; r < 4; ++r) {
      float tm = fmaxf(fmaxf(S[0][r], S[1][r]), fmaxf(S[2][r], S[3][r]));
#pragma unroll
      for (int o = 1; o < 16; o <<= 1) tm = fmaxf(tm, __shfl_xor(tm, o));
      const float mn = fmaxf(mrun[r], tm);
      const float f = __expf(mrun[r] - mn);
      mrun[r] = mn;
      float ps = 0.f;
#pragma unroll
      for (int c = 0; c < 4; ++c) {
        const float p = __expf(S[c][r] - mn);
        S[c][r] = p;
        ps += p;
        accO[c][r] = accO[c][r] * f;
      }
#pragma unroll
      for (int o = 1; o < 16; o <<= 1) ps += __shfl_xor(ps, o);
      lrun[r] = lrun[r] * f + ps;
    }
#pragma unroll
    for (int c = 0; c < 4; ++c)
#pragma unroll
      for (int r = 0; r < 4; ++r) {
        const int ii = 4 * g + r;
        Pw[ii * 64 + ((16 * c + l15) ^ ((ii & 7) << 3))] = f2bf(S[c][r]);
      }
    const bf16x8 pa0 = *(const bf16x8*)&Pw[l15 * 64 + ((g * 8) ^ ((l15 & 7) << 3))];
    const bf16x8 pa1 = *(const bf16x8*)&Pw[l15 * 64 + ((32 + g * 8) ^ ((l15 & 7) << 3))];
#pragma unroll
    for (int c = 0; c < 4; ++c) {
      const u16* vp = &Vt[((size_t)bn64 + 16 * c + l15) * 512 + jb + g * 8];
      accO[c] = __builtin_amdgcn_mfma_f32_16x16x32_bf16(pa0, *(const bf16x8*)vp, accO[c], 0, 0, 0);
      accO[c] = __builtin_amdgcn_mfma_f32_16x16x32_bf16(pa1, *(const bf16x8*)(vp + 32), accO[c], 0, 0, 0);
    }
  }
#pragma unroll
  for (int c = 0; c < 4; ++c)
#pragma unroll
    for (int r = 0; r < 4; ++r) {
      const int ii = 4 * g + r;
      AOb[(size_t)(irow0 + ii) * 8192 + bn64 + 16 * c + l15] = f2bf(accO[c][r] / lrun[r]);
    }
}

// ---------------- LayerNorm over HID=1024, one block per (i,b) row ----------------
__global__ __launch_bounds__(256)
void ln_kernel(const float* __restrict__ X, const float* __restrict__ gam,
               const float* __restrict__ bet, float* __restrict__ out) {
  const int row = blockIdx.x, t = threadIdx.x;
  const float4 x4 = *(const float4*)&X[(size_t)row * HIDN + t * 4];
  float s  = x4.x + x4.y + x4.z + x4.w;
  float sq = x4.x * x4.x + x4.y * x4.y + x4.z * x4.z + x4.w * x4.w;
#pragma unroll
  for (int o = 32; o >= 1; o >>= 1) { s += __shfl_xor(s, o); sq += __shfl_xor(sq, o); }
  __shared__ float red[8];
  const int wv = t >> 6;
  if ((t & 63) == 0) { red[wv * 2] = s; red[wv * 2 + 1] = sq; }
  __syncthreads();
  s  = red[0] + red[2] + red[4] + red[6];
  sq = red[1] + red[3] + red[5] + red[7];
  const float mu  = s * (1.f / HIDN);
  const float var = sq * (1.f / HIDN) - mu * mu;
  const float rs  = rsqrtf(var + LN_EPS);
  const float4 g4 = *(const float4*)&gam[t * 4];
  const float4 b4 = *(const float4*)&bet[t * 4];
  float4 o4;
  o4.x = (x4.x - mu) * rs * g4.x + b4.x;
  o4.y = (x4.y - mu) * rs * g4.y + b4.y;
  o4.z = (x4.z - mu) * rs * g4.z + b4.z;
  o4.w = (x4.w - mu) * rs * g4.w + b4.w;
  *(float4*)&out[(size_t)row * HIDN + t * 4] = o4;
}

extern "C" void kernel_launch(void* const* d_in, const int* in_sizes, int n_in,
                              void* d_out, int out_size, void* d_ws, size_t ws_size,
                              hipStream_t stream) {
  (void)in_sizes; (void)n_in; (void)out_size; (void)ws_size;
  const float* hidden = (const float*)d_in[0];
  const float* pos    = (const float*)d_in[1];
  const float* sege   = (const float*)d_in[2];
  const float* amask  = (const float*)d_in[3];
  const float* qw     = (const float*)d_in[4];
  const float* kw     = (const float*)d_in[5];
  const float* vw     = (const float*)d_in[6];
  const float* rw     = (const float*)d_in[7];
  const float* ow     = (const float*)d_in[8];
  const float* rwb    = (const float*)d_in[9];
  const float* rrb    = (const float*)d_in[10];
  const float* rsb    = (const float*)d_in[11];
  const float* segm   = (const float*)d_in[12];
  const float* gam    = (const float*)d_in[13];
  const float* bet    = (const float*)d_in[14];
  float* out = (float*)d_out;
  char* ws = (char*)d_ws;

  const size_t MiB = 1ull << 20;
  // layout (58.5 MiB total; known-safe ws >= 64 MiB):
  u16*   Wqt = (u16*)(ws);               // [0,2)   bf16 [nd][h]
  u16*   Wkt = (u16*)(ws + 2 * MiB);     // [2,4)
  u16*   Wvt = (u16*)(ws + 4 * MiB);     // [4,6)
  u16*   Wrt = (u16*)(ws + 6 * MiB);     // [6,8)
  u16*   Wob = (u16*)(ws + 8 * MiB);     // [8,10)  bf16 [h][nd] (natural)
  u16*   Qb  = (u16*)(ws + 10 * MiB);    // [10,18)
  u16*   Kb  = (u16*)(ws + 18 * MiB);    // [18,26)
  u16*   Vb  = (u16*)(ws + 26 * MiB);    // [26,34) dead after vtrans
  u16*   AOb = (u16*)(ws + 26 * MiB);    // overlays Vb (written in attn)
  u16*   Krb = (u16*)(ws + 34 * MiB);    // [34,50) dead after attn
  float* X   = (float*)(ws + 34 * MiB);  // overlays Krb (written by O-proj)
  u16*   Vt  = (u16*)(ws + 50 * MiB);    // [50,58)
  float* E   = (float*)(ws + 58 * MiB);  // [58,58.5)

  wtrans_kernel<<<dim3(16, 16, 4), 256, 0, stream>>>(qw, kw, vw, rw, Wqt, Wkt, Wvt, Wrt);
  cvt_bf16_kernel<<<512, 256, 0, stream>>>(ow, Wob);
  // Q,K,V projections fused via z
  gemm_bt<true, false, false><<<dim3(8, 32, 3), 256, 0, stream>>>(
      hidden, Wqt, Wkt, Wvt, Qb, Kb, Vb, nullptr);
  // Kr projection (M=8192)
  gemm_bt<true, false, false><<<dim3(8, 64, 1), 256, 0, stream>>>(
      pos, Wrt, Wrt, Wrt, Krb, Krb, Krb, nullptr);
  vtrans_kernel<<<dim3(128, 8), 256, 0, stream>>>(Vb, Vt);
  seg_e_kernel<<<256, 256, 0, stream>>>(Qb, rsb, segm, E);
  attn_mfma<<<dim3(128, 8), 256, 0, stream>>>(Qb, Kb, Vt, Krb, E, sege, amask, rwb, rrb, AOb);
  // O-projection + residual (fp32 out)
  gemm_bt<false, true, true><<<dim3(8, 32, 1), 256, 0, stream>>>(
      AOb, Wob, Wob, Wob, X, X, X, hidden);
  ln_kernel<<<4096, 256, 0, stream>>>(X, gam, bet, out);
}